// Round 1
// baseline (74.607 us; speedup 1.0000x reference)
//
#include <hip/hip_runtime.h>
#include <hip/hip_fp16.h>

#define NC 32     // num_capsule
#define DC 16     // dim_capsule
#define INC 144   // input capsules
#define IND 8     // input dim
#define NT 512    // threads per block

// LDS layout (bytes):
// hat: [32][144][16] fp16, per-b stride padded to 2320 halves (1160 dwords == 8 mod 32
//      -> the 4 b-groups of a wave hit disjoint bank octets)       = 148480 B
// lg : logits/coefficients [32][146] fp16 (146 halves = 73 dw, odd) =   9344 B
//      (x[144][8] fp32 = 4608 B overlaps lg; x dead before lg live)
// o_s: [32][16] fp32                                                =   2048 B
#define HAT_BS 2320
#define LG_S 146
#define HAT_BYTES (NC * HAT_BS * 2)
#define LG_BYTES (NC * LG_S * 2)
#define O_BYTES (NC * DC * 4)
#define SMEM_BYTES (HAT_BYTES + LG_BYTES + O_BYTES)  // 159872 <= 163840

typedef __attribute__((ext_vector_type(4))) float f4;

__global__ void convw_kernel(const float* __restrict__ W, __half* __restrict__ Wh) {
    int i = blockIdx.x * 256 + threadIdx.x;  // 147456 float4 groups total
    f4 v = reinterpret_cast<const f4*>(W)[i];
    reinterpret_cast<__half2*>(Wh)[2 * i] = __floats2half2_rn(v.x, v.y);
    reinterpret_cast<__half2*>(Wh)[2 * i + 1] = __floats2half2_rn(v.z, v.w);
}

__device__ __forceinline__ float squash16(float s) {
    // 16-lane group (one capsule) reduction of s^2, then squash factor
    float n2 = s * s;
    n2 += __shfl_xor(n2, 1, 16);
    n2 += __shfl_xor(n2, 2, 16);
    n2 += __shfl_xor(n2, 4, 16);
    n2 += __shfl_xor(n2, 8, 16);
    return s * (n2 / ((1.0f + n2) * sqrtf(n2 + 1e-7f)));
}

template <typename WT>
__global__ __launch_bounds__(NT)
void caps_kernel(const float* __restrict__ xg, const WT* __restrict__ Wg,
                 float* __restrict__ out) {
    extern __shared__ char smem[];
    __half* hat = reinterpret_cast<__half*>(smem);
    __half* lg = reinterpret_cast<__half*>(smem + HAT_BYTES);
    float* o_s = reinterpret_cast<float*>(smem + HAT_BYTES + LG_BYTES);
    float* x_s = reinterpret_cast<float*>(lg);  // overlap: x only live in phase H

    const int a = blockIdx.x;
    const int t = threadIdx.x;
    const int b = t >> 4;   // capsule
    const int d = t & 15;   // dim (also 'j' in the b-update pass)

    // ---- load x[a] : 1152 floats ----
    const float* xa = xg + a * (INC * IND);
    x_s[t] = xa[t];
    x_s[t + NT] = xa[t + NT];
    if (t < INC * IND - 2 * NT) x_s[t + 2 * NT] = xa[t + 2 * NT];
    __syncthreads();

    // ---- Phase H: hat[b][c][d] = W[b,c,d,:] . x[c,:]  + s0 accumulation ----
    float s0 = 0.0f;
    {
        const WT* wp = Wg + ((size_t)b * INC * DC + d) * IND;
        __half* hp = hat + b * HAT_BS + d;
        #pragma unroll 4
        for (int c = 0; c < INC; ++c) {
            f4 x0 = *reinterpret_cast<const f4*>(x_s + c * IND);
            f4 x1 = *reinterpret_cast<const f4*>(x_s + c * IND + 4);
            float acc;
            if constexpr (sizeof(WT) == 2) {
                union { f4 v; __half h[8]; } u;
                u.v = *reinterpret_cast<const f4*>(wp);  // 8 halves = 16B
                acc = x0.x * __half2float(u.h[0]);
                acc = fmaf(x0.y, __half2float(u.h[1]), acc);
                acc = fmaf(x0.z, __half2float(u.h[2]), acc);
                acc = fmaf(x0.w, __half2float(u.h[3]), acc);
                acc = fmaf(x1.x, __half2float(u.h[4]), acc);
                acc = fmaf(x1.y, __half2float(u.h[5]), acc);
                acc = fmaf(x1.z, __half2float(u.h[6]), acc);
                acc = fmaf(x1.w, __half2float(u.h[7]), acc);
            } else {
                f4 w0 = *reinterpret_cast<const f4*>(wp);
                f4 w1 = *reinterpret_cast<const f4*>(wp + 4);
                acc = x0.x * w0.x;
                acc = fmaf(x0.y, w0.y, acc);
                acc = fmaf(x0.z, w0.z, acc);
                acc = fmaf(x0.w, w0.w, acc);
                acc = fmaf(x1.x, w1.x, acc);
                acc = fmaf(x1.y, w1.y, acc);
                acc = fmaf(x1.z, w1.z, acc);
                acc = fmaf(x1.w, w1.w, acc);
            }
            s0 += acc;                      // softmax(0) = 1/32 uniform -> s0 free
            hp[c * DC] = __float2half(acc);
            wp += DC * IND;
        }
    }
    s0 *= (1.0f / 32.0f);
    float o = squash16(s0);
    o_s[t] = o;
    __syncthreads();  // hat + o_s visible; x_s region now dead

    // ---- routing iterations: logits master copy in registers (fp32, exact) ----
    float lgr[9];
    #pragma unroll
    for (int k = 0; k < 9; ++k) lgr[k] = 0.0f;

    float outv = 0.0f;
    for (int it = 0; it < 2; ++it) {
        // B-pass: thread (b, j=d) owns c = j+16k. logit[b][c] += o[b,:] . hat[b][c][:]
        f4 ov0 = *reinterpret_cast<const f4*>(o_s + b * DC);
        f4 ov1 = *reinterpret_cast<const f4*>(o_s + b * DC + 4);
        f4 ov2 = *reinterpret_cast<const f4*>(o_s + b * DC + 8);
        f4 ov3 = *reinterpret_cast<const f4*>(o_s + b * DC + 12);
        #pragma unroll
        for (int k = 0; k < 9; ++k) {
            const int c = d + 16 * k;
            const __half* hp = hat + b * HAT_BS + c * DC;
            union { f4 v; __half h[8]; } u0, u1;
            u0.v = *reinterpret_cast<const f4*>(hp);
            u1.v = *reinterpret_cast<const f4*>(hp + 8);
            float dot = ov0.x * __half2float(u0.h[0]);
            dot = fmaf(ov0.y, __half2float(u0.h[1]), dot);
            dot = fmaf(ov0.z, __half2float(u0.h[2]), dot);
            dot = fmaf(ov0.w, __half2float(u0.h[3]), dot);
            dot = fmaf(ov1.x, __half2float(u0.h[4]), dot);
            dot = fmaf(ov1.y, __half2float(u0.h[5]), dot);
            dot = fmaf(ov1.z, __half2float(u0.h[6]), dot);
            dot = fmaf(ov1.w, __half2float(u0.h[7]), dot);
            dot = fmaf(ov2.x, __half2float(u1.h[0]), dot);
            dot = fmaf(ov2.y, __half2float(u1.h[1]), dot);
            dot = fmaf(ov2.z, __half2float(u1.h[2]), dot);
            dot = fmaf(ov2.w, __half2float(u1.h[3]), dot);
            dot = fmaf(ov3.x, __half2float(u1.h[4]), dot);
            dot = fmaf(ov3.y, __half2float(u1.h[5]), dot);
            dot = fmaf(ov3.z, __half2float(u1.h[6]), dot);
            dot = fmaf(ov3.w, __half2float(u1.h[7]), dot);
            lgr[k] += dot;
            lg[b * LG_S + c] = __float2half(lgr[k]);
        }
        __syncthreads();

        // softmax over the 32 capsules, one thread per input capsule c
        if (t < INC) {
            const int c = t;
            float v[NC];
            float m = -1e30f;
            #pragma unroll
            for (int bb = 0; bb < NC; ++bb) {
                v[bb] = __half2float(lg[bb * LG_S + c]);
                m = fmaxf(m, v[bb]);
            }
            float S = 0.0f;
            #pragma unroll
            for (int bb = 0; bb < NC; ++bb) {
                v[bb] = __expf(v[bb] - m);
                S += v[bb];
            }
            float inv = 1.0f / S;
            #pragma unroll
            for (int bb = 0; bb < NC; ++bb)
                lg[bb * LG_S + c] = __float2half(v[bb] * inv);  // in-place cc
        }
        __syncthreads();

        // S-pass: thread (b,d): s = sum_c cc[b][c] * hat[b][c][d]  (thread-local)
        float s = 0.0f;
        {
            const __half* hp = hat + b * HAT_BS + d;
            const __half* cp = lg + b * LG_S;
            #pragma unroll 8
            for (int c = 0; c < INC; ++c)
                s = fmaf(__half2float(cp[c]), __half2float(hp[c * DC]), s);
        }
        float oo = squash16(s);
        if (it == 0) {
            o_s[t] = oo;
            __syncthreads();
        } else {
            outv = oo;
        }
    }
    out[a * (NC * DC) + t] = outv;  // coalesced: out[a][b][d]
}

extern "C" void kernel_launch(void* const* d_in, const int* in_sizes, int n_in,
                              void* d_out, int out_size, void* d_ws, size_t ws_size,
                              hipStream_t stream) {
    const float* x = (const float*)d_in[0];
    const float* W = (const float*)d_in[1];
    float* out = (float*)d_out;

    const size_t WH_BYTES = (size_t)NC * INC * DC * IND * 2;  // 1179648

    if (ws_size >= WH_BYTES) {
        __half* Wh = (__half*)d_ws;
        hipLaunchKernelGGL(convw_kernel, dim3((NC * INC * DC * IND / 4) / 256),
                           dim3(256), 0, stream, W, Wh);
        hipFuncSetAttribute(reinterpret_cast<const void*>(&caps_kernel<__half>),
                            hipFuncAttributeMaxDynamicSharedMemorySize, SMEM_BYTES);
        hipLaunchKernelGGL(caps_kernel<__half>, dim3(512), dim3(NT), SMEM_BYTES,
                           stream, x, Wh, out);
    } else {
        hipFuncSetAttribute(reinterpret_cast<const void*>(&caps_kernel<float>),
                            hipFuncAttributeMaxDynamicSharedMemorySize, SMEM_BYTES);
        hipLaunchKernelGGL(caps_kernel<float>, dim3(512), dim3(NT), SMEM_BYTES,
                           stream, x, W, out);
    }
}